// Round 2
// baseline (192.052 us; speedup 1.0000x reference)
//
#include <hip/hip_runtime.h>
#include <math.h>

#define CCH 512
#define SSQ 2048           // M*T
#define MTOT 4096          // B*S rows

typedef __bf16 bf16;
typedef __bf16 bf16x8 __attribute__((ext_vector_type(8)));
typedef __bf16 bf16x4 __attribute__((ext_vector_type(4)));
typedef float  f32x4  __attribute__((ext_vector_type(4)));

#define AS1 __attribute__((address_space(1)))
#define AS3 __attribute__((address_space(3)))
__device__ __forceinline__ void glds16(const void* g, void* l) {
    __builtin_amdgcn_global_load_lds((const AS1 void*)g, (AS3 void*)l, 16, 0, 0);
}

// ---------------- fused GN-stats (blocks 0..255) + weight transpose (blocks 256..575)
__global__ __launch_bounds__(256) void gnw_kernel(const float* __restrict__ x,
        float* __restrict__ mu, float* __restrict__ rstd,
        const float* __restrict__ w0, const float* __restrict__ w1,
        const float* __restrict__ w2, const float* __restrict__ w3,
        const float* __restrict__ w4, bf16* __restrict__ wT) {
    __shared__ float smem[64*65];
    int tid = threadIdx.x;
    if (blockIdx.x < 256) {
        float* s_sum = smem;
        float* s_sq  = smem + 256;
        int bg = blockIdx.x;
        long base = (long)bg * 8192;
        float sum = 0.f, sq = 0.f;
#pragma unroll
        for (int r = 0; r < 32; ++r) {
            float v = x[base + r*256 + tid];
            sum += v; sq += v*v;
        }
        s_sum[tid] = sum; s_sq[tid] = sq;
        __syncthreads();
        for (int off = 128; off > 0; off >>= 1) {
            if (tid < off) { s_sum[tid] += s_sum[tid+off]; s_sq[tid] += s_sq[tid+off]; }
            __syncthreads();
        }
        if (tid == 0) {
            float m = s_sum[0] * (1.f/8192.f);
            float v = s_sq[0]  * (1.f/8192.f) - m*m;
            mu[bg] = m;
            rstd[bg] = rsqrtf(v + 1e-5f);
        }
    } else {
        int bid = blockIdx.x - 256;
        int z = bid >> 6, r2 = bid & 63;
        int k0 = (r2 >> 3)*64, n0 = (r2 & 7)*64;
        const float* srcs[5] = {w0, w1, w2, w3, w4};
        const float* W = srcs[z];
        bf16* D = wT + (long)z * (CCH*CCH);
        float (*t)[65] = (float(*)[65])smem;
        int cI = tid & 63, r4 = tid >> 6;
#pragma unroll
        for (int p = 0; p < 16; ++p) {
            int kr = p*4 + r4;
            t[kr][cI] = W[(long)(k0+kr)*CCH + n0 + cI];
        }
        __syncthreads();
#pragma unroll
        for (int p = 0; p < 16; ++p) {
            int nr = p*4 + r4;
            D[(long)(n0+nr)*CCH + k0 + cI] = (bf16)t[cI][nr];
        }
    }
}

// ---------------- transpose+norm: x (B,C,S) fp32 -> xnT (B,S,C) bf16
__global__ void tn_kernel(const float* __restrict__ x, const float* __restrict__ mu,
                          const float* __restrict__ rstd, const float* __restrict__ gsc,
                          const float* __restrict__ gbs, bf16* __restrict__ xnT) {
    __shared__ float t[64][65];
    int s0 = blockIdx.x*64, c0 = blockIdx.y*64, b = blockIdx.z;
    int tid = threadIdx.x;
    int cI = tid & 63, r4 = tid >> 6;
#pragma unroll
    for (int p = 0; p < 16; ++p) {
        int cr = p*4 + r4;
        t[cr][cI] = x[((long)(b*CCH + c0 + cr))*SSQ + s0 + cI];
    }
    __syncthreads();
#pragma unroll
    for (int p = 0; p < 16; ++p) {
        int sr = p*4 + r4;
        int c = c0 + cI;
        int g = b*128 + (c >> 2);
        float v = (t[cI][sr] - mu[g]) * rstd[g] * gsc[c] + gbs[c];
        xnT[((long)(b*SSQ + s0 + sr))*CCH + c] = (bf16)v;
    }
}

// ---------------- fused depthwise 3x3 (SAME) q/k/v on (B,S,C) bf16
__global__ __launch_bounds__(256) void dw3_kernel(const bf16* __restrict__ xnT,
        const float* __restrict__ dwq, const float* __restrict__ dwk,
        const float* __restrict__ dwv,
        bf16* __restrict__ yq, bf16* __restrict__ yk, bf16* __restrict__ yv) {
    int tid = threadIdx.x;
    int cc = (tid & 63) * 8;
    int s  = blockIdx.x*4 + (tid >> 6);
    int sl = s & (SSQ-1);
    int b  = s >> 11;
    int m = sl >> 7, t = sl & 127;
    float aq[8] = {}, ak[8] = {}, av[8] = {};
#pragma unroll
    for (int di = 0; di < 3; ++di) {
        int m2 = m + di - 1;
        if ((unsigned)m2 >= 16u) continue;
#pragma unroll
        for (int dj = 0; dj < 3; ++dj) {
            int t2 = t + dj - 1;
            if ((unsigned)t2 >= 128u) continue;
            bf16x8 xv = *(const bf16x8*)(xnT + ((long)(b*SSQ + m2*128 + t2))*CCH + cc);
            int wi = (di*3 + dj)*CCH + cc;
#pragma unroll
            for (int i = 0; i < 8; ++i) {
                float xf = (float)xv[i];
                aq[i] += xf * dwq[wi+i];
                ak[i] += xf * dwk[wi+i];
                av[i] += xf * dwv[wi+i];
            }
        }
    }
    bf16x8 oq, ok, ov;
#pragma unroll
    for (int i = 0; i < 8; ++i) { oq[i] = (bf16)aq[i]; ok[i] = (bf16)ak[i]; ov[i] = (bf16)av[i]; }
    long o = (long)s*CCH + cc;
    *(bf16x8*)(yq + o) = oq;
    *(bf16x8*)(yk + o) = ok;
    *(bf16x8*)(yv + o) = ov;
}

// ---------------- GEMM core, m97 structure: BM=128, BN=NFR*32, BK=64.
template<int NFR>
__device__ __forceinline__ void gemm_core128(const bf16* __restrict__ A,
        const bf16* __restrict__ Wt, int m0, int n0,
        bf16* As, bf16* Bs, f32x4 (&acc)[4][NFR]) {
    int tid = threadIdx.x, lane = tid & 63, wid = tid >> 6;
    int sw = wid & 1, nw = wid >> 1;
    int col = lane & 15, quad = lane >> 4;
    const char* gA[4]; char* ldsA[4];
#pragma unroll
    for (int p = 0; p < 4; ++p) {
        int ci = tid + p*256;              // 1024 chunks of 16B (128 rows x 8)
        int row = ci >> 3;
        int c = (ci & 7) ^ (row & 7);
        gA[p] = (const char*)A + ((long)(m0+row)*CCH + c*8)*2;
        ldsA[p] = (char*)As + ci*16;
    }
    const char* gB[NFR]; char* ldsB[NFR];
#pragma unroll
    for (int p = 0; p < NFR; ++p) {
        int ci = tid + p*256;              // NFR*256 chunks (BN rows x 8)
        int row = ci >> 3;
        int c = (ci & 7) ^ (row & 7);
        gB[p] = (const char*)Wt + ((long)(n0+row)*CCH + c*8)*2;
        ldsB[p] = (char*)Bs + ci*16;
    }
    int rowA = sw*64 + col;
    int rowB = nw*(NFR*16) + col;
    for (int k0 = 0; k0 < CCH; k0 += 64) {
        __syncthreads();
#pragma unroll
        for (int p = 0; p < 4; ++p)   glds16(gA[p] + k0*2, ldsA[p]);
#pragma unroll
        for (int p = 0; p < NFR; ++p) glds16(gB[p] + k0*2, ldsB[p]);
        __syncthreads();
        bf16x8 af[4][2], bfr[NFR][2];
#pragma unroll
        for (int mt = 0; mt < 4; ++mt) {
            int r = rowA + mt*16;
#pragma unroll
            for (int ks = 0; ks < 2; ++ks) {
                int c = (ks*4 + quad) ^ (r & 7);
                af[mt][ks] = *(const bf16x8*)((char*)As + r*128 + c*16);
            }
        }
#pragma unroll
        for (int nt = 0; nt < NFR; ++nt) {
            int r = rowB + nt*16;
#pragma unroll
            for (int ks = 0; ks < 2; ++ks) {
                int c = (ks*4 + quad) ^ (r & 7);
                bfr[nt][ks] = *(const bf16x8*)((char*)Bs + r*128 + c*16);
            }
        }
#pragma unroll
        for (int ks = 0; ks < 2; ++ks)
#pragma unroll
            for (int mt = 0; mt < 4; ++mt)
#pragma unroll
                for (int nt = 0; nt < NFR; ++nt)
                    acc[mt][nt] = __builtin_amdgcn_mfma_f32_16x16x32_bf16(
                        af[mt][ks], bfr[nt][ks], acc[mt][nt], 0,0,0);
    }
}

// ---------------- fused QKV GEMM (128x64 tiles): z selects matrix + epilogue
// z=0: rope*0.125 -> qout (B,S,C); z=1: rope -> kout (B,S,C); z=2: transpose -> vout (B,C,S)
__global__ __launch_bounds__(256) void gemm_qkv(const bf16* __restrict__ Abase,
        const bf16* __restrict__ wT, bf16* __restrict__ qout,
        bf16* __restrict__ kout, bf16* __restrict__ vout) {
    __shared__ bf16 As[128*64];
    __shared__ bf16 Bs[64*64];
    int m0 = blockIdx.x*128, n0 = blockIdx.y*64, z = blockIdx.z;
    f32x4 acc[4][2] = {};
    gemm_core128<2>(Abase + (long)z*MTOT*CCH, wT + (long)z*CCH*CCH, m0, n0, As, Bs, acc);
    int tid = threadIdx.x, lane = tid & 63, wid = tid >> 6;
    int sw = wid & 1, nw = wid >> 1;
    int col = lane & 15, quad = lane >> 4;
    int nb = n0 + nw*32, mb = m0 + sw*64;
    if (z < 2) {
        bf16* outp = z ? kout : qout;
        const float sc = z ? 1.0f : 0.125f;
        float invf = __expf(-(float)col * 0.5756462732485114f);  // 10000^(-col/16)
        bool tHalf = (nb & 32) != 0;
#pragma unroll
        for (int mt = 0; mt < 4; ++mt)
#pragma unroll
            for (int r = 0; r < 4; ++r) {
                int row = mb + mt*16 + quad*4 + r;
                int sl = row & (SSQ-1);
                float pos = tHalf ? (float)(sl & 127) : (float)(sl >> 7);
                float ang = pos * invf;
                float sn, cs;
                __sincosf(ang, &sn, &cs);
                float x1 = acc[mt][0][r], x2 = acc[mt][1][r];
                outp[(long)row*CCH + nb + col]      = (bf16)((x1*cs - x2*sn)*sc);
                outp[(long)row*CCH + nb + 16 + col] = (bf16)((x1*sn + x2*cs)*sc);
            }
    } else {
#pragma unroll
        for (int mt = 0; mt < 4; ++mt)
#pragma unroll
            for (int nt = 0; nt < 2; ++nt) {
                int n = nb + nt*16 + col;
                int row0 = mb + mt*16 + quad*4;
                int bq = row0 >> 11, sl0 = row0 & (SSQ-1);
                bf16x4 pk;
#pragma unroll
                for (int r = 0; r < 4; ++r) pk[r] = (bf16)acc[mt][nt][r];
                *(bf16x4*)(vout + ((long)(bq*CCH + n))*SSQ + sl0) = pk;
            }
    }
}

// ---------------- projection GEMMs (128x64 tiles)
// MODE 3: +bias -> bf16 (B,S,C); MODE 4: +bias+resid -> fp32 (B,C,S) [d_out]
template<int MODE>
__global__ __launch_bounds__(256) void gemm_bf16(const bf16* __restrict__ A,
        const bf16* __restrict__ Wt, const float* __restrict__ bias,
        const float* __restrict__ resid, void* __restrict__ outv) {
    __shared__ bf16 As[128*64];
    __shared__ bf16 Bs[64*64];
    int m0 = blockIdx.x*128, n0 = blockIdx.y*64;
    f32x4 acc[4][2] = {};
    gemm_core128<2>(A, Wt, m0, n0, As, Bs, acc);
    int tid = threadIdx.x, lane = tid & 63, wid = tid >> 6;
    int sw = wid & 1, nw = wid >> 1;
    int col = lane & 15, quad = lane >> 4;
    int nb = n0 + nw*32, mb = m0 + sw*64;
    if (MODE == 3) {
        bf16* outp = (bf16*)outv;
#pragma unroll
        for (int nt = 0; nt < 2; ++nt) {
            int n = nb + nt*16 + col;
            float bv = bias[n];
#pragma unroll
            for (int mt = 0; mt < 4; ++mt)
#pragma unroll
                for (int r = 0; r < 4; ++r)
                    outp[(long)(mb + mt*16 + quad*4 + r)*CCH + n] = (bf16)(acc[mt][nt][r] + bv);
        }
    } else {
        float* outp = (float*)outv;
#pragma unroll
        for (int mt = 0; mt < 4; ++mt)
#pragma unroll
            for (int nt = 0; nt < 2; ++nt) {
                int n = nb + nt*16 + col;
                float bv = bias[n];
                int row0 = mb + mt*16 + quad*4;
                int b = row0 >> 11, sl0 = row0 & (SSQ-1);
                long off = ((long)(b*CCH + n))*SSQ + sl0;
                float4 rr = *(const float4*)(resid + off);
                float4 o4;
                o4.x = acc[mt][nt][0] + bv + rr.x;
                o4.y = acc[mt][nt][1] + bv + rr.y;
                o4.z = acc[mt][nt][2] + bv + rr.z;
                o4.w = acc[mt][nt][3] + bv + rr.w;
                *(float4*)(outp + off) = o4;
            }
    }
}

// ---------------- MFMA flash attention v6: BARRIER-FREE main loop.
// 4 waves = (qh x kh): each wave 32q x 32k per 64-key tile.
// K/V fragments read DIRECTLY from global (L2-resident: 512KB per (b,h));
// register prefetch distance 1 tile; P transpose via per-wave private LDS;
// cross-kh partial-O merge through LDS at the end (fixed-max softmax => adds).
// q,k: bf16 (B,S,C); v: bf16 (B,C,S); o: bf16 (B,S,C)
#define PSTR 40             // P row stride in bf16 (80B: 16B-aligned, conflict-lite)

template<int MASKED>
__device__ __forceinline__ void attn_tile(
        const bf16x8 (&KC)[2][2], const bf16x8 (&VC)[4],
        bf16x8 (&KN)[2][2], bf16x8 (&VN)[4], int tn,
        const char* const (&kp)[2][2], const char* const (&vp)[4],
        const bf16x8 (&qf)[2][2], const f32x4 (&vm)[2],
        bf16* pw, int col, int quad,
        f32x4 (&of)[2][4], float& ls0, float& ls1) {
    if (tn < 32) {                      // prefetch next tile into KN/VN
        long tko = (long)tn * 65536;
#pragma unroll
        for (int sub = 0; sub < 2; ++sub)
#pragma unroll
            for (int dc = 0; dc < 2; ++dc)
                KN[sub][dc] = *(const bf16x8*)(kp[sub][dc] + tko);
        long tvo = (long)tn * 128;
#pragma unroll
        for (int dt = 0; dt < 4; ++dt)
            VN[dt] = *(const bf16x8*)(vp[dt] + tvo);
    }
    // ---- S^T = K Q^T  (32k x 32q per wave)
    f32x4 sc[2][2] = {};
#pragma unroll
    for (int dc = 0; dc < 2; ++dc)
#pragma unroll
        for (int sub = 0; sub < 2; ++sub)
#pragma unroll
            for (int qt = 0; qt < 2; ++qt)
                sc[sub][qt] = __builtin_amdgcn_mfma_f32_16x16x32_bf16(
                    KC[sub][dc], qf[qt][dc], sc[sub][qt], 0,0,0);
    // ---- exp (* mask) + lane lsum + pack P into LDS (transpose)
#pragma unroll
    for (int sub = 0; sub < 2; ++sub)
#pragma unroll
        for (int qt = 0; qt < 2; ++qt) {
            bf16x4 pk;
#pragma unroll
            for (int r = 0; r < 4; ++r) {
                float p = __expf(sc[sub][qt][r]);
                if (MASKED) p *= vm[sub][r];
                if (qt) ls1 += p; else ls0 += p;
                pk[r] = (bf16)p;
            }
            *(bf16x4*)(pw + (qt*16 + col)*PSTR + sub*16 + quad*4) = pk;
        }
    bf16x8 pf0 = *(const bf16x8*)(pw + col*PSTR + quad*8);
    bf16x8 pf1 = *(const bf16x8*)(pw + (16 + col)*PSTR + quad*8);
    // ---- O += P V  (32 keys in one K-step)
#pragma unroll
    for (int dt = 0; dt < 4; ++dt) {
        of[0][dt] = __builtin_amdgcn_mfma_f32_16x16x32_bf16(pf0, VC[dt], of[0][dt], 0,0,0);
        of[1][dt] = __builtin_amdgcn_mfma_f32_16x16x32_bf16(pf1, VC[dt], of[1][dt], 0,0,0);
    }
}

__global__ __launch_bounds__(256, 2) void attn_kernel(
        const bf16* __restrict__ qb, const bf16* __restrict__ kb,
        const bf16* __restrict__ vb, const int* __restrict__ lengths,
        bf16* __restrict__ o) {
    __shared__ bf16 Ps[4][32*PSTR];          // per-wave private P buffers (10KB)
    __shared__ float Om[2][2][4][16][17];    // kh=1 partial O  (34.8KB)
    __shared__ float Lm[2][2][16];           // kh=1 partial lsum
    // bid low 4 bits = (b,h) so all q-tiles of one (b,h) share an XCD (L2 locality)
    int bid = blockIdx.x;
    int bh = bid & 15, qtb = bid >> 4;
    int h = bh >> 1, b = bh & 1;
    int tid = threadIdx.x, wid = tid >> 6, lane = tid & 63;
    int col = lane & 15, quad = lane >> 4;
    int qh = wid & 1, kh = wid >> 1;
    int q0 = qtb*64;
    int lenb = lengths[b];

    // mask (odd tiles only: keys mod 128 in [64,128); even tiles always valid, len>=64)
    f32x4 vm[2];
#pragma unroll
    for (int sub = 0; sub < 2; ++sub)
#pragma unroll
        for (int r = 0; r < 4; ++r)
            vm[sub][r] = (64 + kh*32 + sub*16 + quad*4 + r < lenb) ? 1.f : 0.f;

    const bf16* qp = qb + (long)(b*SSQ)*CCH + h*64;
    bf16x8 qf[2][2];
#pragma unroll
    for (int qt = 0; qt < 2; ++qt)
#pragma unroll
        for (int dc = 0; dc < 2; ++dc)
            qf[qt][dc] = *(const bf16x8*)(qp + (long)(q0 + qh*32 + qt*16 + col)*CCH + dc*32 + quad*8);

    const char* kp[2][2];
#pragma unroll
    for (int sub = 0; sub < 2; ++sub)
#pragma unroll
        for (int dc = 0; dc < 2; ++dc)
            kp[sub][dc] = (const char*)(kb + ((long)(b*SSQ + kh*32 + sub*16 + col))*CCH + h*64 + dc*32 + quad*8);
    const char* vp[4];
#pragma unroll
    for (int dt = 0; dt < 4; ++dt)
        vp[dt] = (const char*)(vb + ((long)(b*CCH + h*64 + dt*16 + col))*SSQ + kh*32 + quad*8);

    f32x4 of[2][4] = {};
    float ls0 = 0.f, ls1 = 0.f;
    bf16* pw = Ps[wid];

    bf16x8 kA[2][2], vA[4], kB[2][2], vB[4];
#pragma unroll
    for (int sub = 0; sub < 2; ++sub)
#pragma unroll
        for (int dc = 0; dc < 2; ++dc)
            kA[sub][dc] = *(const bf16x8*)(kp[sub][dc]);
#pragma unroll
    for (int dt = 0; dt < 4; ++dt)
        vA[dt] = *(const bf16x8*)(vp[dt]);

    for (int t = 0; t < 32; t += 2) {
        attn_tile<0>(kA, vA, kB, vB, t+1, kp, vp, qf, vm, pw, col, quad, of, ls0, ls1);
        attn_tile<1>(kB, vB, kA, vA, t+2, kp, vp, qf, vm, pw, col, quad, of, ls0, ls1);
    }

    // per-wave lsum reduction: every lane -> full sum over this wave's 32-key half
    ls0 += __shfl_xor(ls0, 16); ls0 += __shfl_xor(ls0, 32);
    ls1 += __shfl_xor(ls1, 16); ls1 += __shfl_xor(ls1, 32);

    // cross-kh merge (fixed-max softmax: partial O and lsum simply add)
    if (kh == 1) {
#pragma unroll
        for (int qt = 0; qt < 2; ++qt)
#pragma unroll
            for (int dt = 0; dt < 4; ++dt)
#pragma unroll
                for (int r = 0; r < 4; ++r)
                    Om[qh][qt][dt][quad*4 + r][col] = of[qt][dt][r];
        if (lane < 16) { Lm[qh][0][lane] = ls0; Lm[qh][1][lane] = ls1; }
    }
    __syncthreads();
    if (kh == 0) {
        float i0 = 1.f / (ls0 + Lm[qh][0][col]);
        float i1 = 1.f / (ls1 + Lm[qh][1][col]);
        bf16* ob = o + (long)(b*SSQ + q0 + qh*32)*CCH + h*64;
#pragma unroll
        for (int qt = 0; qt < 2; ++qt) {
            float inv = qt ? i1 : i0;
            float ir[4];
#pragma unroll
            for (int r = 0; r < 4; ++r) ir[r] = __shfl(inv, quad*4 + r);
#pragma unroll
            for (int dt = 0; dt < 4; ++dt)
#pragma unroll
                for (int r = 0; r < 4; ++r) {
                    float v = of[qt][dt][r] + Om[qh][qt][dt][quad*4 + r][col];
                    ob[(long)(qt*16 + quad*4 + r)*CCH + dt*16 + col] = (bf16)(v * ir[r]);
                }
        }
    }
}

extern "C" void kernel_launch(void* const* d_in, const int* in_sizes, int n_in,
                              void* d_out, int out_size, void* d_ws, size_t ws_size,
                              hipStream_t stream) {
    const float* x        = (const float*)d_in[0];
    const int*   lengths  = (const int*)  d_in[1];
    const float* gn_scale = (const float*)d_in[2];
    const float* gn_bias  = (const float*)d_in[3];
    const float* dw_q     = (const float*)d_in[4];
    const float* dw_k     = (const float*)d_in[5];
    const float* dw_v     = (const float*)d_in[6];
    const float* pw_q     = (const float*)d_in[7];
    const float* pw_k     = (const float*)d_in[8];
    const float* pw_v     = (const float*)d_in[9];
    const float* attn_w   = (const float*)d_in[10];
    const float* attn_b   = (const float*)d_in[11];
    const float* out_w    = (const float*)d_in[12];
    const float* out_b    = (const float*)d_in[13];
    float* out = (float*)d_out;

    char* w = (char*)d_ws;
    float* mu   = (float*)w;
    float* rstd = (float*)(w + 1024);
    bf16* wT    = (bf16*)(w + 4096);          // 5 * 512KB
    bf16* wTa = wT + 3*CCH*CCH;
    bf16* wTo = wT + 4*CCH*CCH;
    bf16* xnT  = (bf16*)(w + 0x00300000);
    bf16* yT   = (bf16*)(w + 0x00700000);     // yq|yk|yv contiguous, 4MB each
    bf16* qbf  = (bf16*)(w + 0x01300000);
    bf16* kbf  = (bf16*)(w + 0x01700000);
    bf16* vbf  = (bf16*)(w + 0x01B00000);
    bf16* obf  = (bf16*)(w + 0x01F00000);
    bf16* tmpb = (bf16*)(w + 0x02300000);

    gnw_kernel<<<576, 256, 0, stream>>>(x, mu, rstd, pw_q, pw_k, pw_v, attn_w, out_w, wT);
    tn_kernel<<<dim3(32,8,2), 256, 0, stream>>>(x, mu, rstd, gn_scale, gn_bias, xnT);
    dw3_kernel<<<MTOT/4, 256, 0, stream>>>(xnT, dw_q, dw_k, dw_v,
                                           yT, yT + (long)MTOT*CCH, yT + (long)2*MTOT*CCH);

    gemm_qkv<<<dim3(MTOT/128, CCH/64, 3), 256, 0, stream>>>(yT, wT, qbf, kbf, vbf);

    attn_kernel<<<512, 256, 0, stream>>>(qbf, kbf, vbf, lengths, obf);

    dim3 gg(MTOT/128, CCH/64);
    gemm_bf16<3><<<gg, 256, 0, stream>>>(obf, wTa, attn_b, nullptr, tmpb);
    gemm_bf16<4><<<gg, 256, 0, stream>>>(tmpb, wTo, out_b, x, out);
}

// Round 3
// 170.461 us; speedup vs baseline: 1.1267x; 1.1267x over previous
//
#include <hip/hip_runtime.h>
#include <math.h>

#define CCH 512
#define SSQ 2048           // M*T
#define MTOT 4096          // B*S rows

typedef __bf16 bf16;
typedef __bf16 bf16x8 __attribute__((ext_vector_type(8)));
typedef __bf16 bf16x4 __attribute__((ext_vector_type(4)));
typedef float  f32x4  __attribute__((ext_vector_type(4)));

#define AS1 __attribute__((address_space(1)))
#define AS3 __attribute__((address_space(3)))
__device__ __forceinline__ void glds16(const void* g, void* l) {
    __builtin_amdgcn_global_load_lds((const AS1 void*)g, (AS3 void*)l, 16, 0, 0);
}

// ---------------- fused GN-stats (blocks 0..255) + weight transpose (blocks 256..575)
__global__ __launch_bounds__(256) void gnw_kernel(const float* __restrict__ x,
        float* __restrict__ mu, float* __restrict__ rstd,
        const float* __restrict__ w0, const float* __restrict__ w1,
        const float* __restrict__ w2, const float* __restrict__ w3,
        const float* __restrict__ w4, bf16* __restrict__ wT) {
    __shared__ float smem[64*65];
    int tid = threadIdx.x;
    if (blockIdx.x < 256) {
        float* s_sum = smem;
        float* s_sq  = smem + 256;
        int bg = blockIdx.x;
        long base = (long)bg * 8192;
        float sum = 0.f, sq = 0.f;
#pragma unroll
        for (int r = 0; r < 32; ++r) {
            float v = x[base + r*256 + tid];
            sum += v; sq += v*v;
        }
        s_sum[tid] = sum; s_sq[tid] = sq;
        __syncthreads();
        for (int off = 128; off > 0; off >>= 1) {
            if (tid < off) { s_sum[tid] += s_sum[tid+off]; s_sq[tid] += s_sq[tid+off]; }
            __syncthreads();
        }
        if (tid == 0) {
            float m = s_sum[0] * (1.f/8192.f);
            float v = s_sq[0]  * (1.f/8192.f) - m*m;
            mu[bg] = m;
            rstd[bg] = rsqrtf(v + 1e-5f);
        }
    } else {
        int bid = blockIdx.x - 256;
        int z = bid >> 6, r2 = bid & 63;
        int k0 = (r2 >> 3)*64, n0 = (r2 & 7)*64;
        const float* srcs[5] = {w0, w1, w2, w3, w4};
        const float* W = srcs[z];
        bf16* D = wT + (long)z * (CCH*CCH);
        float (*t)[65] = (float(*)[65])smem;
        int cI = tid & 63, r4 = tid >> 6;
#pragma unroll
        for (int p = 0; p < 16; ++p) {
            int kr = p*4 + r4;
            t[kr][cI] = W[(long)(k0+kr)*CCH + n0 + cI];
        }
        __syncthreads();
#pragma unroll
        for (int p = 0; p < 16; ++p) {
            int nr = p*4 + r4;
            D[(long)(n0+nr)*CCH + k0 + cI] = (bf16)t[cI][nr];
        }
    }
}

// ---------------- transpose+norm: x (B,C,S) fp32 -> xnT (B,S,C) bf16
__global__ void tn_kernel(const float* __restrict__ x, const float* __restrict__ mu,
                          const float* __restrict__ rstd, const float* __restrict__ gsc,
                          const float* __restrict__ gbs, bf16* __restrict__ xnT) {
    __shared__ float t[64][65];
    int s0 = blockIdx.x*64, c0 = blockIdx.y*64, b = blockIdx.z;
    int tid = threadIdx.x;
    int cI = tid & 63, r4 = tid >> 6;
#pragma unroll
    for (int p = 0; p < 16; ++p) {
        int cr = p*4 + r4;
        t[cr][cI] = x[((long)(b*CCH + c0 + cr))*SSQ + s0 + cI];
    }
    __syncthreads();
#pragma unroll
    for (int p = 0; p < 16; ++p) {
        int sr = p*4 + r4;
        int c = c0 + cI;
        int g = b*128 + (c >> 2);
        float v = (t[cI][sr] - mu[g]) * rstd[g] * gsc[c] + gbs[c];
        xnT[((long)(b*SSQ + s0 + sr))*CCH + c] = (bf16)v;
    }
}

// ---------------- fused depthwise 3x3 (SAME) q/k/v on (B,S,C) bf16
__global__ __launch_bounds__(256) void dw3_kernel(const bf16* __restrict__ xnT,
        const float* __restrict__ dwq, const float* __restrict__ dwk,
        const float* __restrict__ dwv,
        bf16* __restrict__ yq, bf16* __restrict__ yk, bf16* __restrict__ yv) {
    int tid = threadIdx.x;
    int cc = (tid & 63) * 8;
    int s  = blockIdx.x*4 + (tid >> 6);
    int sl = s & (SSQ-1);
    int b  = s >> 11;
    int m = sl >> 7, t = sl & 127;
    float aq[8] = {}, ak[8] = {}, av[8] = {};
#pragma unroll
    for (int di = 0; di < 3; ++di) {
        int m2 = m + di - 1;
        if ((unsigned)m2 >= 16u) continue;
#pragma unroll
        for (int dj = 0; dj < 3; ++dj) {
            int t2 = t + dj - 1;
            if ((unsigned)t2 >= 128u) continue;
            bf16x8 xv = *(const bf16x8*)(xnT + ((long)(b*SSQ + m2*128 + t2))*CCH + cc);
            int wi = (di*3 + dj)*CCH + cc;
#pragma unroll
            for (int i = 0; i < 8; ++i) {
                float xf = (float)xv[i];
                aq[i] += xf * dwq[wi+i];
                ak[i] += xf * dwk[wi+i];
                av[i] += xf * dwv[wi+i];
            }
        }
    }
    bf16x8 oq, ok, ov;
#pragma unroll
    for (int i = 0; i < 8; ++i) { oq[i] = (bf16)aq[i]; ok[i] = (bf16)ak[i]; ov[i] = (bf16)av[i]; }
    long o = (long)s*CCH + cc;
    *(bf16x8*)(yq + o) = oq;
    *(bf16x8*)(yk + o) = ok;
    *(bf16x8*)(yv + o) = ov;
}

// ---------------- GEMM core, m97 structure: BM=128, BN=NFR*32, BK=64.
template<int NFR>
__device__ __forceinline__ void gemm_core128(const bf16* __restrict__ A,
        const bf16* __restrict__ Wt, int m0, int n0,
        bf16* As, bf16* Bs, f32x4 (&acc)[4][NFR]) {
    int tid = threadIdx.x, lane = tid & 63, wid = tid >> 6;
    int sw = wid & 1, nw = wid >> 1;
    int col = lane & 15, quad = lane >> 4;
    const char* gA[4]; char* ldsA[4];
#pragma unroll
    for (int p = 0; p < 4; ++p) {
        int ci = tid + p*256;              // 1024 chunks of 16B (128 rows x 8)
        int row = ci >> 3;
        int c = (ci & 7) ^ (row & 7);
        gA[p] = (const char*)A + ((long)(m0+row)*CCH + c*8)*2;
        ldsA[p] = (char*)As + ci*16;
    }
    const char* gB[NFR]; char* ldsB[NFR];
#pragma unroll
    for (int p = 0; p < NFR; ++p) {
        int ci = tid + p*256;              // NFR*256 chunks (BN rows x 8)
        int row = ci >> 3;
        int c = (ci & 7) ^ (row & 7);
        gB[p] = (const char*)Wt + ((long)(n0+row)*CCH + c*8)*2;
        ldsB[p] = (char*)Bs + ci*16;
    }
    int rowA = sw*64 + col;
    int rowB = nw*(NFR*16) + col;
    for (int k0 = 0; k0 < CCH; k0 += 64) {
        __syncthreads();
#pragma unroll
        for (int p = 0; p < 4; ++p)   glds16(gA[p] + k0*2, ldsA[p]);
#pragma unroll
        for (int p = 0; p < NFR; ++p) glds16(gB[p] + k0*2, ldsB[p]);
        __syncthreads();
        bf16x8 af[4][2], bfr[NFR][2];
#pragma unroll
        for (int mt = 0; mt < 4; ++mt) {
            int r = rowA + mt*16;
#pragma unroll
            for (int ks = 0; ks < 2; ++ks) {
                int c = (ks*4 + quad) ^ (r & 7);
                af[mt][ks] = *(const bf16x8*)((char*)As + r*128 + c*16);
            }
        }
#pragma unroll
        for (int nt = 0; nt < NFR; ++nt) {
            int r = rowB + nt*16;
#pragma unroll
            for (int ks = 0; ks < 2; ++ks) {
                int c = (ks*4 + quad) ^ (r & 7);
                bfr[nt][ks] = *(const bf16x8*)((char*)Bs + r*128 + c*16);
            }
        }
#pragma unroll
        for (int ks = 0; ks < 2; ++ks)
#pragma unroll
            for (int mt = 0; mt < 4; ++mt)
#pragma unroll
                for (int nt = 0; nt < NFR; ++nt)
                    acc[mt][nt] = __builtin_amdgcn_mfma_f32_16x16x32_bf16(
                        af[mt][ks], bfr[nt][ks], acc[mt][nt], 0,0,0);
    }
}

// ---------------- fused QKV GEMM (128x64 tiles): z selects matrix + epilogue
__global__ __launch_bounds__(256) void gemm_qkv(const bf16* __restrict__ Abase,
        const bf16* __restrict__ wT, bf16* __restrict__ qout,
        bf16* __restrict__ kout, bf16* __restrict__ vout) {
    __shared__ bf16 As[128*64];
    __shared__ bf16 Bs[64*64];
    int m0 = blockIdx.x*128, n0 = blockIdx.y*64, z = blockIdx.z;
    f32x4 acc[4][2] = {};
    gemm_core128<2>(Abase + (long)z*MTOT*CCH, wT + (long)z*CCH*CCH, m0, n0, As, Bs, acc);
    int tid = threadIdx.x, lane = tid & 63, wid = tid >> 6;
    int sw = wid & 1, nw = wid >> 1;
    int col = lane & 15, quad = lane >> 4;
    int nb = n0 + nw*32, mb = m0 + sw*64;
    if (z < 2) {
        bf16* outp = z ? kout : qout;
        const float sc = z ? 1.0f : 0.125f;
        float invf = __expf(-(float)col * 0.5756462732485114f);  // 10000^(-col/16)
        bool tHalf = (nb & 32) != 0;
#pragma unroll
        for (int mt = 0; mt < 4; ++mt)
#pragma unroll
            for (int r = 0; r < 4; ++r) {
                int row = mb + mt*16 + quad*4 + r;
                int sl = row & (SSQ-1);
                float pos = tHalf ? (float)(sl & 127) : (float)(sl >> 7);
                float ang = pos * invf;
                float sn, cs;
                __sincosf(ang, &sn, &cs);
                float x1 = acc[mt][0][r], x2 = acc[mt][1][r];
                outp[(long)row*CCH + nb + col]      = (bf16)((x1*cs - x2*sn)*sc);
                outp[(long)row*CCH + nb + 16 + col] = (bf16)((x1*sn + x2*cs)*sc);
            }
    } else {
#pragma unroll
        for (int mt = 0; mt < 4; ++mt)
#pragma unroll
            for (int nt = 0; nt < 2; ++nt) {
                int n = nb + nt*16 + col;
                int row0 = mb + mt*16 + quad*4;
                int bq = row0 >> 11, sl0 = row0 & (SSQ-1);
                bf16x4 pk;
#pragma unroll
                for (int r = 0; r < 4; ++r) pk[r] = (bf16)acc[mt][nt][r];
                *(bf16x4*)(vout + ((long)(bq*CCH + n))*SSQ + sl0) = pk;
            }
    }
}

// ---------------- projection GEMMs (128x64 tiles)
template<int MODE>
__global__ __launch_bounds__(256) void gemm_bf16(const bf16* __restrict__ A,
        const bf16* __restrict__ Wt, const float* __restrict__ bias,
        const float* __restrict__ resid, void* __restrict__ outv) {
    __shared__ bf16 As[128*64];
    __shared__ bf16 Bs[64*64];
    int m0 = blockIdx.x*128, n0 = blockIdx.y*64;
    f32x4 acc[4][2] = {};
    gemm_core128<2>(A, Wt, m0, n0, As, Bs, acc);
    int tid = threadIdx.x, lane = tid & 63, wid = tid >> 6;
    int sw = wid & 1, nw = wid >> 1;
    int col = lane & 15, quad = lane >> 4;
    int nb = n0 + nw*32, mb = m0 + sw*64;
    if (MODE == 3) {
        bf16* outp = (bf16*)outv;
#pragma unroll
        for (int nt = 0; nt < 2; ++nt) {
            int n = nb + nt*16 + col;
            float bv = bias[n];
#pragma unroll
            for (int mt = 0; mt < 4; ++mt)
#pragma unroll
                for (int r = 0; r < 4; ++r)
                    outp[(long)(mb + mt*16 + quad*4 + r)*CCH + n] = (bf16)(acc[mt][nt][r] + bv);
        }
    } else {
        float* outp = (float*)outv;
#pragma unroll
        for (int mt = 0; mt < 4; ++mt)
#pragma unroll
            for (int nt = 0; nt < 2; ++nt) {
                int n = nb + nt*16 + col;
                float bv = bias[n];
                int row0 = mb + mt*16 + quad*4;
                int b = row0 >> 11, sl0 = row0 & (SSQ-1);
                long off = ((long)(b*CCH + n))*SSQ + sl0;
                float4 rr = *(const float4*)(resid + off);
                float4 o4;
                o4.x = acc[mt][nt][0] + bv + rr.x;
                o4.y = acc[mt][nt][1] + bv + rr.y;
                o4.z = acc[mt][nt][2] + bv + rr.z;
                o4.w = acc[mt][nt][3] + bv + rr.w;
                *(float4*)(outp + off) = o4;
            }
    }
}

// ---------------- MFMA flash attention v7: wave owns 32 q-rows (2x fragment
// reuse), KV-split x2 for occupancy, global_load_lds double-buffered staging
// with stage-before-compute (one barrier/tile), mask folded into MFMA C-init,
// fp32 partial O/lsum to workspace, separate merge kernel.
// q,k: bf16 (B,S,C); v: bf16 (B,C,S)
__global__ __launch_bounds__(256) void attn_kernel(
        const bf16* __restrict__ qb, const bf16* __restrict__ kb,
        const bf16* __restrict__ vb, const int* __restrict__ lengths,
        float* __restrict__ opart, float* __restrict__ lpart) {
    __shared__ char KV[2][16384];        // [buf][ K 64x128B | V^T 64x128B ]
    __shared__ bf16 Ps[4][32*72];        // per-wave P: 32q x 64k (+pad)
    // bid low 4 bits = bh so all blocks of one (b,h) share an XCD (L2 locality)
    int bid = blockIdx.x;
    int bh = bid & 15;
    int n  = bid >> 4;                   // 0..31
    int qt = n & 15, kvh = n >> 4;
    int b = bh >> 3, h = bh & 7;
    int tid = threadIdx.x, wid = tid >> 6, lane = tid & 63;
    int col = lane & 15, quad = lane >> 4;
    int lenb = lengths[b];
    int q0 = qt*128 + wid*32;
    int k0 = kvh*1024;

    // staging: 1024 chunks of 16B (512 K + 512 V); LDS linear, source swizzled
    const char* gp[4]; long gstep[4]; int ldsoff[4];
#pragma unroll
    for (int p = 0; p < 4; ++p) {
        int idx = tid + p*256;
        int isV = idx >> 9;
        int rem = idx & 511;             // 64 rows x 8 chunks
        int r = rem >> 3;
        int csrc = (rem & 7) ^ (r & 7);
        if (!isV) { gp[p] = (const char*)kb + ((long)(b*SSQ + k0 + r))*1024 + h*128 + csrc*16; gstep[p] = 65536; }
        else      { gp[p] = (const char*)vb + ((long)(b*CCH + h*64 + r))*4096 + (long)k0*2 + csrc*16; gstep[p] = 128; }
        ldsoff[p] = idx*16;
    }

    // mask bias for odd GLOBAL tiles (keys%128 in [64,128)); even tiles always valid (len>=64)
    f32x4 mb[4];
#pragma unroll
    for (int sub = 0; sub < 4; ++sub)
#pragma unroll
        for (int r = 0; r < 4; ++r)
            mb[sub][r] = (64 + sub*16 + quad*4 + r < lenb) ? 0.f : -10000.f;

    const bf16* qp = qb + (long)(b*SSQ)*CCH + h*64;
    bf16x8 qf[2][2];
#pragma unroll
    for (int qt2 = 0; qt2 < 2; ++qt2)
#pragma unroll
        for (int dc = 0; dc < 2; ++dc)
            qf[qt2][dc] = *(const bf16x8*)(qp + (long)(q0 + qt2*16 + col)*CCH + dc*32 + quad*8);

    f32x4 of[2][4] = {};
    float ls0 = 0.f, ls1 = 0.f;
    bf16* pw = Ps[wid];
    int cswz = col & 7;

    // prologue: stage tile 0 into buf 0
#pragma unroll
    for (int p = 0; p < 4; ++p) glds16(gp[p], KV[0] + ldsoff[p]);
    __syncthreads();                     // implicit vmcnt(0) drain

    for (int t = 0; t < 16; ++t) {
        // issue next tile's staging first (overlaps compute below)
        if (t < 15) {
#pragma unroll
            for (int p = 0; p < 4; ++p)
                glds16(gp[p] + (long)(t+1)*gstep[p], KV[(t+1) & 1] + ldsoff[p]);
        }
        const bf16* K = (const bf16*)(KV[t & 1]);
        const bf16* V = (const bf16*)(KV[t & 1] + 8192);
        bool masked = ((kvh*16 + t) & 1) != 0;
        // ---- S^T = K Q^T  (64k x 32q per wave), mask via C-init
        f32x4 sc[4][2];
#pragma unroll
        for (int sub = 0; sub < 4; ++sub)
#pragma unroll
            for (int qt2 = 0; qt2 < 2; ++qt2)
                sc[sub][qt2] = masked ? mb[sub] : (f32x4){0.f,0.f,0.f,0.f};
#pragma unroll
        for (int sub = 0; sub < 4; ++sub)
#pragma unroll
            for (int dc = 0; dc < 2; ++dc) {
                bf16x8 kf = *(const bf16x8*)((const char*)K + (sub*16 + col)*128 + (((dc*4+quad) ^ cswz))*16);
#pragma unroll
                for (int qt2 = 0; qt2 < 2; ++qt2)
                    sc[sub][qt2] = __builtin_amdgcn_mfma_f32_16x16x32_bf16(
                        kf, qf[qt2][dc], sc[sub][qt2], 0,0,0);
            }
        // ---- exp + lane lsum + pack P (transpose via per-wave LDS)
#pragma unroll
        for (int sub = 0; sub < 4; ++sub)
#pragma unroll
            for (int qt2 = 0; qt2 < 2; ++qt2) {
                bf16x4 pk;
#pragma unroll
                for (int r = 0; r < 4; ++r) {
                    float p = __expf(sc[sub][qt2][r]);
                    if (qt2) ls1 += p; else ls0 += p;
                    pk[r] = (bf16)p;
                }
                *(bf16x4*)(pw + (qt2*16 + col)*72 + sub*16 + quad*4) = pk;
            }
        // ---- O += P V
#pragma unroll
        for (int ks = 0; ks < 2; ++ks) {
            bf16x8 pf0 = *(const bf16x8*)(pw + col*72 + ks*32 + quad*8);
            bf16x8 pf1 = *(const bf16x8*)(pw + (16 + col)*72 + ks*32 + quad*8);
#pragma unroll
            for (int dt = 0; dt < 4; ++dt) {
                bf16x8 vf = *(const bf16x8*)((const char*)V + (dt*16 + col)*128 + (((ks*4+quad) ^ cswz))*16);
                of[0][dt] = __builtin_amdgcn_mfma_f32_16x16x32_bf16(pf0, vf, of[0][dt], 0,0,0);
                of[1][dt] = __builtin_amdgcn_mfma_f32_16x16x32_bf16(pf1, vf, of[1][dt], 0,0,0);
            }
        }
        __syncthreads();                 // drains next-tile DMA + protects buffers
    }

    // lsum: reduce over quads -> each lane holds row-sum for q = q0 + qt2*16 + col
    ls0 += __shfl_xor(ls0, 16); ls0 += __shfl_xor(ls0, 32);
    ls1 += __shfl_xor(ls1, 16); ls1 += __shfl_xor(ls1, 32);

    // store fp32 partials: opart[kvh][bh][q][d]
    float* op = opart + ((long)(kvh*16 + bh)*2048)*64;
#pragma unroll
    for (int qt2 = 0; qt2 < 2; ++qt2)
#pragma unroll
        for (int dt = 0; dt < 4; ++dt)
#pragma unroll
            for (int r = 0; r < 4; ++r)
                op[(long)(q0 + qt2*16 + quad*4 + r)*64 + dt*16 + col] = of[qt2][dt][r];
    if (quad == 0) {
        float* lp = lpart + (long)(kvh*16 + bh)*2048;
        lp[q0 + col]      = ls0;
        lp[q0 + 16 + col] = ls1;
    }
}

// ---------------- merge the two KV-half partials -> bf16 (B,S,C)
__global__ __launch_bounds__(256) void attn_merge(const float* __restrict__ opart,
        const float* __restrict__ lpart, bf16* __restrict__ o) {
    int idx = blockIdx.x*256 + threadIdx.x;      // (bh, q, dchunk): 16*2048*16
    int dchunk = idx & 15;
    int q = (idx >> 4) & 2047;
    int bh = idx >> 15;
    long o0 = ((long)bh*2048 + q)*64 + dchunk*4;
    float4 a = *(const float4*)(opart + o0);
    float4 c = *(const float4*)(opart + o0 + (long)16*2048*64);
    float inv = 1.f / (lpart[bh*2048 + q] + lpart[(16 + bh)*2048 + q]);
    bf16x4 pk;
    pk[0] = (bf16)((a.x + c.x) * inv);
    pk[1] = (bf16)((a.y + c.y) * inv);
    pk[2] = (bf16)((a.z + c.z) * inv);
    pk[3] = (bf16)((a.w + c.w) * inv);
    int b = bh >> 3, h = bh & 7;
    *(bf16x4*)(o + ((long)(b*SSQ + q))*CCH + h*64 + dchunk*4) = pk;
}

extern "C" void kernel_launch(void* const* d_in, const int* in_sizes, int n_in,
                              void* d_out, int out_size, void* d_ws, size_t ws_size,
                              hipStream_t stream) {
    const float* x        = (const float*)d_in[0];
    const int*   lengths  = (const int*)  d_in[1];
    const float* gn_scale = (const float*)d_in[2];
    const float* gn_bias  = (const float*)d_in[3];
    const float* dw_q     = (const float*)d_in[4];
    const float* dw_k     = (const float*)d_in[5];
    const float* dw_v     = (const float*)d_in[6];
    const float* pw_q     = (const float*)d_in[7];
    const float* pw_k     = (const float*)d_in[8];
    const float* pw_v     = (const float*)d_in[9];
    const float* attn_w   = (const float*)d_in[10];
    const float* attn_b   = (const float*)d_in[11];
    const float* out_w    = (const float*)d_in[12];
    const float* out_b    = (const float*)d_in[13];
    float* out = (float*)d_out;

    char* w = (char*)d_ws;
    float* mu   = (float*)w;
    float* rstd = (float*)(w + 1024);
    bf16* wT    = (bf16*)(w + 4096);          // 5 * 512KB, ends ~0x281000
    bf16* wTa = wT + 3*CCH*CCH;
    bf16* wTo = wT + 4*CCH*CCH;
    float* lpart = (float*)(w + 0x00290000);  // 256KB (gap before xnT)
    bf16* xnT  = (bf16*)(w + 0x00300000);     // dead after dw3 -> reused as opart
    bf16* yT   = (bf16*)(w + 0x00700000);     // yq|yk|yv contiguous, 4MB each (dead after gemm_qkv)
    float* opart = (float*)(w + 0x00300000);  // 16 MiB exactly (2*16*2048*64 fp32)
    bf16* qbf  = (bf16*)(w + 0x01300000);
    bf16* kbf  = (bf16*)(w + 0x01700000);
    bf16* vbf  = (bf16*)(w + 0x01B00000);
    bf16* obf  = (bf16*)(w + 0x01F00000);
    bf16* tmpb = (bf16*)(w + 0x02300000);

    gnw_kernel<<<576, 256, 0, stream>>>(x, mu, rstd, pw_q, pw_k, pw_v, attn_w, out_w, wT);
    tn_kernel<<<dim3(32,8,2), 256, 0, stream>>>(x, mu, rstd, gn_scale, gn_bias, xnT);
    dw3_kernel<<<MTOT/4, 256, 0, stream>>>(xnT, dw_q, dw_k, dw_v,
                                           yT, yT + (long)MTOT*CCH, yT + (long)2*MTOT*CCH);

    gemm_qkv<<<dim3(MTOT/128, CCH/64, 3), 256, 0, stream>>>(yT, wT, qbf, kbf, vbf);

    attn_kernel<<<512, 256, 0, stream>>>(qbf, kbf, vbf, lengths, opart, lpart);
    attn_merge<<<2048, 256, 0, stream>>>(opart, lpart, obf);

    dim3 gg(MTOT/128, CCH/64);
    gemm_bf16<3><<<gg, 256, 0, stream>>>(obf, wTa, attn_b, nullptr, tmpb);
    gemm_bf16<4><<<gg, 256, 0, stream>>>(tmpb, wTo, out_b, x, out);
}

// Round 4
// 168.149 us; speedup vs baseline: 1.1422x; 1.0137x over previous
//
#include <hip/hip_runtime.h>
#include <math.h>

#define CCH 512
#define SSQ 2048           // M*T
#define MTOT 4096          // B*S rows

typedef __bf16 bf16;
typedef __bf16 bf16x8 __attribute__((ext_vector_type(8)));
typedef __bf16 bf16x4 __attribute__((ext_vector_type(4)));
typedef float  f32x4  __attribute__((ext_vector_type(4)));

#define AS1 __attribute__((address_space(1)))
#define AS3 __attribute__((address_space(3)))
__device__ __forceinline__ void glds16(const void* g, void* l) {
    __builtin_amdgcn_global_load_lds((const AS1 void*)g, (AS3 void*)l, 16, 0, 0);
}

// ---------------- fused prep: GN-stats (0..255) + weight transpose (256..575)
// + combined bias bc = attn_b@out_w + out_b (576..577) + bf16 copy of attn_w (578..641)
__global__ __launch_bounds__(256) void gnw_kernel(const float* __restrict__ x,
        float* __restrict__ mu, float* __restrict__ rstd,
        const float* __restrict__ w0, const float* __restrict__ w1,
        const float* __restrict__ w2, const float* __restrict__ w3,
        const float* __restrict__ w4, bf16* __restrict__ wT,
        const float* __restrict__ attnb, const float* __restrict__ outb,
        float* __restrict__ bcv) {
    __shared__ float smem[64*65];
    int tid = threadIdx.x;
    if (blockIdx.x < 256) {
        float* s_sum = smem;
        float* s_sq  = smem + 256;
        int bg = blockIdx.x;
        long base = (long)bg * 8192;
        float sum = 0.f, sq = 0.f;
#pragma unroll
        for (int r = 0; r < 32; ++r) {
            float v = x[base + r*256 + tid];
            sum += v; sq += v*v;
        }
        s_sum[tid] = sum; s_sq[tid] = sq;
        __syncthreads();
        for (int off = 128; off > 0; off >>= 1) {
            if (tid < off) { s_sum[tid] += s_sum[tid+off]; s_sq[tid] += s_sq[tid+off]; }
            __syncthreads();
        }
        if (tid == 0) {
            float m = s_sum[0] * (1.f/8192.f);
            float v = s_sq[0]  * (1.f/8192.f) - m*m;
            mu[bg] = m;
            rstd[bg] = rsqrtf(v + 1e-5f);
        }
    } else if (blockIdx.x < 576) {
        int bid = blockIdx.x - 256;
        int z = bid >> 6, r2 = bid & 63;
        int k0 = (r2 >> 3)*64, n0 = (r2 & 7)*64;
        const float* srcs[5] = {w0, w1, w2, w3, w4};
        const float* W = srcs[z];
        bf16* D = wT + (long)z * (CCH*CCH);
        float (*t)[65] = (float(*)[65])smem;
        int cI = tid & 63, r4 = tid >> 6;
#pragma unroll
        for (int p = 0; p < 16; ++p) {
            int kr = p*4 + r4;
            t[kr][cI] = W[(long)(k0+kr)*CCH + n0 + cI];
        }
        __syncthreads();
#pragma unroll
        for (int p = 0; p < 16; ++p) {
            int nr = p*4 + r4;
            D[(long)(n0+nr)*CCH + k0 + cI] = (bf16)t[cI][nr];
        }
    } else if (blockIdx.x < 578) {
        // bc[n] = out_b[n] + sum_j attn_b[j] * out_w[j][n]
        int n = (blockIdx.x - 576)*256 + tid;
        float a = outb[n];
        for (int j = 0; j < 512; ++j)
            a = fmaf(attnb[j], w4[(long)j*CCH + n], a);
        bcv[n] = a;
    } else {
        // straight bf16 copy of attn_w into wT slot 5
        bf16* wAc = wT + (long)5*CCH*CCH;
        int base = (blockIdx.x - 578)*4096 + tid;
#pragma unroll
        for (int p = 0; p < 16; ++p)
            wAc[base + p*256] = (bf16)w3[base + p*256];
    }
}

// ---------------- transpose+norm: x (B,C,S) fp32 -> xnT (B,S,C) bf16
__global__ void tn_kernel(const float* __restrict__ x, const float* __restrict__ mu,
                          const float* __restrict__ rstd, const float* __restrict__ gsc,
                          const float* __restrict__ gbs, bf16* __restrict__ xnT) {
    __shared__ float t[64][65];
    int s0 = blockIdx.x*64, c0 = blockIdx.y*64, b = blockIdx.z;
    int tid = threadIdx.x;
    int cI = tid & 63, r4 = tid >> 6;
#pragma unroll
    for (int p = 0; p < 16; ++p) {
        int cr = p*4 + r4;
        t[cr][cI] = x[((long)(b*CCH + c0 + cr))*SSQ + s0 + cI];
    }
    __syncthreads();
#pragma unroll
    for (int p = 0; p < 16; ++p) {
        int sr = p*4 + r4;
        int c = c0 + cI;
        int g = b*128 + (c >> 2);
        float v = (t[cI][sr] - mu[g]) * rstd[g] * gsc[c] + gbs[c];
        xnT[((long)(b*SSQ + s0 + sr))*CCH + c] = (bf16)v;
    }
}

// ---------------- fused depthwise 3x3 (SAME) q/k/v on (B,S,C) bf16
__global__ __launch_bounds__(256) void dw3_kernel(const bf16* __restrict__ xnT,
        const float* __restrict__ dwq, const float* __restrict__ dwk,
        const float* __restrict__ dwv,
        bf16* __restrict__ yq, bf16* __restrict__ yk, bf16* __restrict__ yv) {
    int tid = threadIdx.x;
    int cc = (tid & 63) * 8;
    int s  = blockIdx.x*4 + (tid >> 6);
    int sl = s & (SSQ-1);
    int b  = s >> 11;
    int m = sl >> 7, t = sl & 127;
    float aq[8] = {}, ak[8] = {}, av[8] = {};
#pragma unroll
    for (int di = 0; di < 3; ++di) {
        int m2 = m + di - 1;
        if ((unsigned)m2 >= 16u) continue;
#pragma unroll
        for (int dj = 0; dj < 3; ++dj) {
            int t2 = t + dj - 1;
            if ((unsigned)t2 >= 128u) continue;
            bf16x8 xv = *(const bf16x8*)(xnT + ((long)(b*SSQ + m2*128 + t2))*CCH + cc);
            int wi = (di*3 + dj)*CCH + cc;
#pragma unroll
            for (int i = 0; i < 8; ++i) {
                float xf = (float)xv[i];
                aq[i] += xf * dwq[wi+i];
                ak[i] += xf * dwk[wi+i];
                av[i] += xf * dwv[wi+i];
            }
        }
    }
    bf16x8 oq, ok, ov;
#pragma unroll
    for (int i = 0; i < 8; ++i) { oq[i] = (bf16)aq[i]; ok[i] = (bf16)ak[i]; ov[i] = (bf16)av[i]; }
    long o = (long)s*CCH + cc;
    *(bf16x8*)(yq + o) = oq;
    *(bf16x8*)(yk + o) = ok;
    *(bf16x8*)(yv + o) = ov;
}

// ---------------- GEMM core, m97 structure: BM=128, BN=NFR*32, BK=64.
template<int NFR>
__device__ __forceinline__ void gemm_core128(const bf16* __restrict__ A,
        const bf16* __restrict__ Wt, int m0, int n0,
        bf16* As, bf16* Bs, f32x4 (&acc)[4][NFR]) {
    int tid = threadIdx.x, lane = tid & 63, wid = tid >> 6;
    int sw = wid & 1, nw = wid >> 1;
    int col = lane & 15, quad = lane >> 4;
    const char* gA[4]; char* ldsA[4];
#pragma unroll
    for (int p = 0; p < 4; ++p) {
        int ci = tid + p*256;              // 1024 chunks of 16B (128 rows x 8)
        int row = ci >> 3;
        int c = (ci & 7) ^ (row & 7);
        gA[p] = (const char*)A + ((long)(m0+row)*CCH + c*8)*2;
        ldsA[p] = (char*)As + ci*16;
    }
    const char* gB[NFR]; char* ldsB[NFR];
#pragma unroll
    for (int p = 0; p < NFR; ++p) {
        int ci = tid + p*256;              // NFR*256 chunks (BN rows x 8)
        int row = ci >> 3;
        int c = (ci & 7) ^ (row & 7);
        gB[p] = (const char*)Wt + ((long)(n0+row)*CCH + c*8)*2;
        ldsB[p] = (char*)Bs + ci*16;
    }
    int rowA = sw*64 + col;
    int rowB = nw*(NFR*16) + col;
    for (int k0 = 0; k0 < CCH; k0 += 64) {
        __syncthreads();
#pragma unroll
        for (int p = 0; p < 4; ++p)   glds16(gA[p] + k0*2, ldsA[p]);
#pragma unroll
        for (int p = 0; p < NFR; ++p) glds16(gB[p] + k0*2, ldsB[p]);
        __syncthreads();
        bf16x8 af[4][2], bfr[NFR][2];
#pragma unroll
        for (int mt = 0; mt < 4; ++mt) {
            int r = rowA + mt*16;
#pragma unroll
            for (int ks = 0; ks < 2; ++ks) {
                int c = (ks*4 + quad) ^ (r & 7);
                af[mt][ks] = *(const bf16x8*)((char*)As + r*128 + c*16);
            }
        }
#pragma unroll
        for (int nt = 0; nt < NFR; ++nt) {
            int r = rowB + nt*16;
#pragma unroll
            for (int ks = 0; ks < 2; ++ks) {
                int c = (ks*4 + quad) ^ (r & 7);
                bfr[nt][ks] = *(const bf16x8*)((char*)Bs + r*128 + c*16);
            }
        }
#pragma unroll
        for (int ks = 0; ks < 2; ++ks)
#pragma unroll
            for (int mt = 0; mt < 4; ++mt)
#pragma unroll
                for (int nt = 0; nt < NFR; ++nt)
                    acc[mt][nt] = __builtin_amdgcn_mfma_f32_16x16x32_bf16(
                        af[mt][ks], bfr[nt][ks], acc[mt][nt], 0,0,0);
    }
}

// ---------------- fused QKV GEMM (128x64 tiles) + combined-weight prep
// z=0: rope*0.125 -> qout; z=1: rope -> kout; z=2: transpose -> vout (B,C,S)
// z=3 (blocks x<4): WcT = (Wa@Wo)^T from wTo,wAc -> wT slot 6
__global__ __launch_bounds__(256) void gemm_qkv(const bf16* __restrict__ Abase,
        bf16* __restrict__ wT, bf16* __restrict__ qout,
        bf16* __restrict__ kout, bf16* __restrict__ vout) {
    __shared__ bf16 As[128*64];
    __shared__ bf16 Bs[64*64];
    int z = blockIdx.z;
    if (z == 3 && blockIdx.x >= 4) return;
    int m0 = blockIdx.x*128, n0 = blockIdx.y*64;
    const bf16* Aop = (z < 3) ? Abase + (long)z*MTOT*CCH : wT + (long)4*CCH*CCH;
    const bf16* Wop = (z < 3) ? wT + (long)z*CCH*CCH   : wT + (long)5*CCH*CCH;
    f32x4 acc[4][2] = {};
    gemm_core128<2>(Aop, Wop, m0, n0, As, Bs, acc);
    int tid = threadIdx.x, lane = tid & 63, wid = tid >> 6;
    int sw = wid & 1, nw = wid >> 1;
    int col = lane & 15, quad = lane >> 4;
    int nb = n0 + nw*32, mb = m0 + sw*64;
    if (z == 3) {
        bf16* wCt = wT + (long)6*CCH*CCH;
#pragma unroll
        for (int nt = 0; nt < 2; ++nt) {
            int n = nb + nt*16 + col;
#pragma unroll
            for (int mt = 0; mt < 4; ++mt)
#pragma unroll
                for (int r = 0; r < 4; ++r)
                    wCt[(long)(mb + mt*16 + quad*4 + r)*CCH + n] = (bf16)acc[mt][nt][r];
        }
    } else if (z < 2) {
        bf16* outp = z ? kout : qout;
        const float sc = z ? 1.0f : 0.125f;
        float invf = __expf(-(float)col * 0.5756462732485114f);  // 10000^(-col/16)
        bool tHalf = (nb & 32) != 0;
#pragma unroll
        for (int mt = 0; mt < 4; ++mt)
#pragma unroll
            for (int r = 0; r < 4; ++r) {
                int row = mb + mt*16 + quad*4 + r;
                int sl = row & (SSQ-1);
                float pos = tHalf ? (float)(sl & 127) : (float)(sl >> 7);
                float ang = pos * invf;
                float sn, cs;
                __sincosf(ang, &sn, &cs);
                float x1 = acc[mt][0][r], x2 = acc[mt][1][r];
                outp[(long)row*CCH + nb + col]      = (bf16)((x1*cs - x2*sn)*sc);
                outp[(long)row*CCH + nb + 16 + col] = (bf16)((x1*sn + x2*cs)*sc);
            }
    } else {
#pragma unroll
        for (int mt = 0; mt < 4; ++mt)
#pragma unroll
            for (int nt = 0; nt < 2; ++nt) {
                int n = nb + nt*16 + col;
                int row0 = mb + mt*16 + quad*4;
                int bq = row0 >> 11, sl0 = row0 & (SSQ-1);
                bf16x4 pk;
#pragma unroll
                for (int r = 0; r < 4; ++r) pk[r] = (bf16)acc[mt][nt][r];
                *(bf16x4*)(vout + ((long)(bq*CCH + n))*SSQ + sl0) = pk;
            }
    }
}

// ---------------- projection GEMM (128x64): +bias+resid -> fp32 (B,C,S) [d_out]
__global__ __launch_bounds__(256) void gemm_out(const bf16* __restrict__ A,
        const bf16* __restrict__ Wt, const float* __restrict__ bias,
        const float* __restrict__ resid, float* __restrict__ outp) {
    __shared__ bf16 As[128*64];
    __shared__ bf16 Bs[64*64];
    int m0 = blockIdx.x*128, n0 = blockIdx.y*64;
    f32x4 acc[4][2] = {};
    gemm_core128<2>(A, Wt, m0, n0, As, Bs, acc);
    int tid = threadIdx.x, lane = tid & 63, wid = tid >> 6;
    int sw = wid & 1, nw = wid >> 1;
    int col = lane & 15, quad = lane >> 4;
    int nb = n0 + nw*32, mb = m0 + sw*64;
#pragma unroll
    for (int mt = 0; mt < 4; ++mt)
#pragma unroll
        for (int nt = 0; nt < 2; ++nt) {
            int n = nb + nt*16 + col;
            float bv = bias[n];
            int row0 = mb + mt*16 + quad*4;
            int b = row0 >> 11, sl0 = row0 & (SSQ-1);
            long off = ((long)(b*CCH + n))*SSQ + sl0;
            float4 rr = *(const float4*)(resid + off);
            float4 o4;
            o4.x = acc[mt][nt][0] + bv + rr.x;
            o4.y = acc[mt][nt][1] + bv + rr.y;
            o4.z = acc[mt][nt][2] + bv + rr.z;
            o4.w = acc[mt][nt][3] + bv + rr.w;
            *(float4*)(outp + off) = o4;
        }
}

// ---------------- MFMA flash attention v8: in-block KV-split.
// 512 threads = 8 waves = 4 q-subtiles(32q) x 2 kv-halves(1024 keys each).
// Double-buffered global_load_lds staging (stage-before-compute, 1 barrier/tile),
// mask folded into MFMA C-init, cross-half merge through LDS at the end.
// q,k: bf16 (B,S,C); v: bf16 (B,C,S); o: bf16 (B,S,C)
__global__ __launch_bounds__(512) void attn_kernel(
        const bf16* __restrict__ qb, const bf16* __restrict__ kb,
        const bf16* __restrict__ vb, const int* __restrict__ lengths,
        bf16* __restrict__ o) {
    __shared__ char KVs[2][32768];       // [buf][half][K 8K | V^T 8K]
    __shared__ bf16 Ps[8][32*72];        // per-wave P: 32q x 64k (+pad)
    __shared__ float Lm[4][2][16];
    // bid low 4 bits = bh: all 16 q-blocks of one (b,h) map to one XCD (%8)
    int bid = blockIdx.x;
    int bh = bid & 15, qtb = bid >> 4;
    int b = bh >> 3, h = bh & 7;
    int tid = threadIdx.x, wid = tid >> 6, lane = tid & 63;
    int col = lane & 15, quad = lane >> 4;
    int qh = wid & 3, kh = wid >> 2;
    int q0 = qtb*128 + qh*32;
    int lenb = lengths[b];

    // staging: 2048 chunks of 16B per buffer (2 halves x (K 512 + V 512))
    const char* gp[4]; long gstep[4]; int ldsoff[4];
#pragma unroll
    for (int p = 0; p < 4; ++p) {
        int idx = tid + p*512;
        int half = idx >> 10;
        int rem2 = idx & 1023;
        int isV = rem2 >> 9;
        int rem = rem2 & 511;            // 64 rows x 8 chunks
        int r = rem >> 3;
        int csrc = (rem & 7) ^ (r & 7);
        if (!isV) { gp[p] = (const char*)kb + ((long)(b*SSQ + half*1024 + r))*1024 + h*128 + csrc*16; gstep[p] = 65536; }
        else      { gp[p] = (const char*)vb + ((long)(b*CCH + h*64 + r))*4096 + half*2048 + csrc*16;  gstep[p] = 128; }
        ldsoff[p] = idx*16;
    }

    // mask bias for odd global key-tiles (keys%128 in [64,128)); len>=64 => even tiles valid
    f32x4 mb[4];
#pragma unroll
    for (int sub = 0; sub < 4; ++sub)
#pragma unroll
        for (int r = 0; r < 4; ++r)
            mb[sub][r] = (64 + sub*16 + quad*4 + r < lenb) ? 0.f : -10000.f;

    const bf16* qp = qb + (long)(b*SSQ)*CCH + h*64;
    bf16x8 qf[2][2];
#pragma unroll
    for (int qt2 = 0; qt2 < 2; ++qt2)
#pragma unroll
        for (int dc = 0; dc < 2; ++dc)
            qf[qt2][dc] = *(const bf16x8*)(qp + (long)(q0 + qt2*16 + col)*CCH + dc*32 + quad*8);

    f32x4 of[2][4] = {};
    float ls0 = 0.f, ls1 = 0.f;
    bf16* pw = Ps[wid];
    int cswz = col & 7;

    // prologue: stage tile 0 into buf 0
#pragma unroll
    for (int p = 0; p < 4; ++p) glds16(gp[p], KVs[0] + ldsoff[p]);
    __syncthreads();                     // implicit vmcnt(0) drain

    for (int t = 0; t < 16; ++t) {
        if (t < 15) {
#pragma unroll
            for (int p = 0; p < 4; ++p)
                glds16(gp[p] + (long)(t+1)*gstep[p], KVs[(t+1) & 1] + ldsoff[p]);
        }
        const bf16* K = (const bf16*)(KVs[t & 1] + kh*16384);
        const bf16* V = (const bf16*)(KVs[t & 1] + kh*16384 + 8192);
        bool masked = (t & 1) != 0;      // global tile kh*16+t, kh*16 even
        // ---- S^T = K Q^T  (64k x 32q per wave), mask via C-init
        f32x4 sc[4][2];
#pragma unroll
        for (int sub = 0; sub < 4; ++sub)
#pragma unroll
            for (int qt2 = 0; qt2 < 2; ++qt2)
                sc[sub][qt2] = masked ? mb[sub] : (f32x4){0.f,0.f,0.f,0.f};
#pragma unroll
        for (int sub = 0; sub < 4; ++sub)
#pragma unroll
            for (int dc = 0; dc < 2; ++dc) {
                bf16x8 kf = *(const bf16x8*)((const char*)K + (sub*16 + col)*128 + (((dc*4+quad) ^ cswz))*16);
#pragma unroll
                for (int qt2 = 0; qt2 < 2; ++qt2)
                    sc[sub][qt2] = __builtin_amdgcn_mfma_f32_16x16x32_bf16(
                        kf, qf[qt2][dc], sc[sub][qt2], 0,0,0);
            }
        // ---- exp + lane lsum + pack P (transpose via per-wave LDS)
#pragma unroll
        for (int sub = 0; sub < 4; ++sub)
#pragma unroll
            for (int qt2 = 0; qt2 < 2; ++qt2) {
                bf16x4 pk;
#pragma unroll
                for (int r = 0; r < 4; ++r) {
                    float p = __expf(sc[sub][qt2][r]);
                    if (qt2) ls1 += p; else ls0 += p;
                    pk[r] = (bf16)p;
                }
                *(bf16x4*)(pw + (qt2*16 + col)*72 + sub*16 + quad*4) = pk;
            }
        // ---- O += P V
#pragma unroll
        for (int ks = 0; ks < 2; ++ks) {
            bf16x8 pf0 = *(const bf16x8*)(pw + col*72 + ks*32 + quad*8);
            bf16x8 pf1 = *(const bf16x8*)(pw + (16 + col)*72 + ks*32 + quad*8);
#pragma unroll
            for (int dt = 0; dt < 4; ++dt) {
                bf16x8 vf = *(const bf16x8*)((const char*)V + (dt*16 + col)*128 + (((ks*4+quad) ^ cswz))*16);
                of[0][dt] = __builtin_amdgcn_mfma_f32_16x16x32_bf16(pf0, vf, of[0][dt], 0,0,0);
                of[1][dt] = __builtin_amdgcn_mfma_f32_16x16x32_bf16(pf1, vf, of[1][dt], 0,0,0);
            }
        }
        __syncthreads();                 // drains next-tile DMA + protects buffers
    }

    // lsum: reduce over quads; lane col holds row-sum for q = q0 + qt2*16 + col
    ls0 += __shfl_xor(ls0, 16); ls0 += __shfl_xor(ls0, 32);
    ls1 += __shfl_xor(ls1, 16); ls1 += __shfl_xor(ls1, 32);

    // cross-half merge through LDS (fixed-max softmax: partials add)
    float* Om = (float*)KVs;             // 32KB overlay, safe after last barrier
    if (kh == 1) {
#pragma unroll
        for (int qt2 = 0; qt2 < 2; ++qt2)
#pragma unroll
            for (int dt = 0; dt < 4; ++dt)
#pragma unroll
                for (int r = 0; r < 4; ++r)
                    Om[(qh*32 + qt2*16 + quad*4 + r)*64 + dt*16 + col] = of[qt2][dt][r];
        if (quad == 0) { Lm[qh][0][col] = ls0; Lm[qh][1][col] = ls1; }
    }
    __syncthreads();
    if (kh == 0) {
        float i0 = 1.f / (ls0 + Lm[qh][0][col]);
        float i1 = 1.f / (ls1 + Lm[qh][1][col]);
        bf16* ob = o + (long)(b*SSQ + q0)*CCH + h*64;
#pragma unroll
        for (int qt2 = 0; qt2 < 2; ++qt2) {
            float inv = qt2 ? i1 : i0;
            float ir[4];
#pragma unroll
            for (int r = 0; r < 4; ++r) ir[r] = __shfl(inv, quad*4 + r);
#pragma unroll
            for (int dt = 0; dt < 4; ++dt)
#pragma unroll
                for (int r = 0; r < 4; ++r) {
                    float v = of[qt2][dt][r] + Om[(qh*32 + qt2*16 + quad*4 + r)*64 + dt*16 + col];
                    ob[(long)(qt2*16 + quad*4 + r)*CCH + dt*16 + col] = (bf16)(v * ir[r]);
                }
        }
    }
}

extern "C" void kernel_launch(void* const* d_in, const int* in_sizes, int n_in,
                              void* d_out, int out_size, void* d_ws, size_t ws_size,
                              hipStream_t stream) {
    const float* x        = (const float*)d_in[0];
    const int*   lengths  = (const int*)  d_in[1];
    const float* gn_scale = (const float*)d_in[2];
    const float* gn_bias  = (const float*)d_in[3];
    const float* dw_q     = (const float*)d_in[4];
    const float* dw_k     = (const float*)d_in[5];
    const float* dw_v     = (const float*)d_in[6];
    const float* pw_q     = (const float*)d_in[7];
    const float* pw_k     = (const float*)d_in[8];
    const float* pw_v     = (const float*)d_in[9];
    const float* attn_w   = (const float*)d_in[10];
    const float* attn_b   = (const float*)d_in[11];
    const float* out_w    = (const float*)d_in[12];
    const float* out_b    = (const float*)d_in[13];
    float* out = (float*)d_out;

    char* w = (char*)d_ws;
    float* mu   = (float*)w;
    float* rstd = (float*)(w + 1024);
    float* bcv  = (float*)(w + 2048);
    bf16* wT    = (bf16*)(w + 4096);          // 7 slots x 512KB:
                                              // 0..2 pw_{q,k,v}^T, 3 Wa^T, 4 Wo^T, 5 Wa, 6 Wc^T
    bf16* wCt = wT + (long)6*CCH*CCH;
    bf16* xnT  = (bf16*)(w + 0x00400000);
    bf16* yT   = (bf16*)(w + 0x00800000);     // yq|yk|yv contiguous, 4MB each
    bf16* qbf  = (bf16*)(w + 0x01400000);
    bf16* kbf  = (bf16*)(w + 0x01800000);
    bf16* vbf  = (bf16*)(w + 0x01C00000);
    bf16* obf  = (bf16*)(w + 0x02000000);

    gnw_kernel<<<642, 256, 0, stream>>>(x, mu, rstd, pw_q, pw_k, pw_v, attn_w, out_w,
                                        wT, attn_b, out_b, bcv);
    tn_kernel<<<dim3(32,8,2), 256, 0, stream>>>(x, mu, rstd, gn_scale, gn_bias, xnT);
    dw3_kernel<<<MTOT/4, 256, 0, stream>>>(xnT, dw_q, dw_k, dw_v,
                                           yT, yT + (long)MTOT*CCH, yT + (long)2*MTOT*CCH);

    gemm_qkv<<<dim3(MTOT/128, CCH/64, 4), 256, 0, stream>>>(yT, wT, qbf, kbf, vbf);

    attn_kernel<<<256, 512, 0, stream>>>(qbf, kbf, vbf, lengths, obf);

    gemm_out<<<dim3(MTOT/128, CCH/64), 256, 0, stream>>>(obf, wCt, bcv, x, out);
}